// Round 2
// baseline (4830.439 us; speedup 1.0000x reference)
//
#include <hip/hip_runtime.h>
#include <hip/hip_bf16.h>
#include <cstdint>
#include <cstddef>

#define BB 64
#define TT 512
#define DD 256
#define HH 512
#define G4 2048   // 4*H

typedef __bf16 bf16x8 __attribute__((ext_vector_type(8)));
typedef __bf16 bf16x4 __attribute__((ext_vector_type(4)));
typedef float  f32x4  __attribute__((ext_vector_type(4)));

__device__ __forceinline__ float sigf(float x) {
  return 1.0f / (1.0f + __expf(-x));
}

// Convert x fp32 [B][T][D] -> bf16 (same layout) in ws.
__global__ void cvt_x_kernel(const float* __restrict__ x, __bf16* __restrict__ xb) {
  int i = (blockIdx.x * 256 + threadIdx.x) * 4;
  float4 v = *(const float4*)(x + i);
  bf16x4 o;
  o[0] = (__bf16)v.x; o[1] = (__bf16)v.y; o[2] = (__bf16)v.z; o[3] = (__bf16)v.w;
  *(bf16x4*)(xb + i) = o;
}

// Persistent bidirectional LSTM.
// Grid: 64 blocks x 256 threads. dir = blockIdx>>5, s = blockIdx&31 owns hidden
// units [16s,16s+16). Wave = M-tile (16 batch rows). Weights live in VGPR/AGPR
// as pre-gathered MFMA B-fragments.
// Sync per step: per-block flag word (release-fence + relaxed store);
// consumers: every wave spins with RELAXED agent loads on all 32 flags
// (lanes poll flags[lane&31], __all ballot), then ONE acquire fence.
// No acquire-side __syncthreads. h/out/hsb stores are non-temporal so the
// release fence's wbL2 has (nearly) nothing dirty to write back.
__launch_bounds__(256, 1)
__global__ void lstm_kernel(const __bf16* __restrict__ xb,
                            const float* __restrict__ Wf, const float* __restrict__ Uf,
                            const float* __restrict__ bf_,
                            const float* __restrict__ Wb, const float* __restrict__ Ub,
                            const float* __restrict__ bb_,
                            __bf16* __restrict__ hbuf,           // [2 dir][2 phase][64][512]
                            unsigned int* __restrict__ flags,    // [2][32] stride 32 uints
                            float* __restrict__ out,             // d_out
                            __bf16* __restrict__ hsb) {          // [T][B][H] bwd halves
  const int bx  = blockIdx.x;
  const int dir = bx >> 5;
  const int s   = bx & 31;
  const float* Wd = dir ? Wb : Wf;
  const float* Ud = dir ? Ub : Uf;
  const float* bd = dir ? bb_ : bf_;
  unsigned int* flbase = flags + (size_t)dir * 32 * 32;   // 32 flags, 128B apart
  unsigned int* myflag = flbase + (size_t)s * 32;
  __bf16* hb = hbuf + (size_t)dir * 2 * BB * HH;

  const int tid  = threadIdx.x;
  const int mt   = tid >> 6;      // wave id = M-tile
  const int lane = tid & 63;
  const int j    = lane & 15;     // A row offset / B col / D col
  const int q    = lane >> 4;     // quad
  const int colg = s * 16 + j;    // hidden unit index this lane owns

  // ---- gather weight B-fragments (one-time) ----
  bf16x8 wfrag[4][24];
#pragma unroll
  for (int g = 0; g < 4; ++g) {
    const int col = g * HH + colg;
#pragma unroll
    for (int kt = 0; kt < 24; ++kt) {
      bf16x8 v;
#pragma unroll
      for (int e = 0; e < 8; ++e) {
        const int k = kt * 32 + q * 8 + e;
        const float w = (k < DD) ? Wd[(size_t)k * G4 + col]
                                 : Ud[(size_t)(k - DD) * G4 + col];
        v[e] = (__bf16)w;
      }
      wfrag[g][kt] = v;
    }
  }
  float bg[4];
#pragma unroll
  for (int g = 0; g < 4; ++g) bg[g] = bd[g * HH + colg];

  float cst[4] = {0.f, 0.f, 0.f, 0.f};   // cell state, rows mt*16+q*4+r
  const size_t outTail = (size_t)BB * TT * HH;
  unsigned int* pollp = flbase + (size_t)(lane & 31) * 32;

  for (int tau = 0; tau < TT; ++tau) {
    const int t = dir ? (TT - 1 - tau) : tau;

    // x-part (independent of h): issue before the spin
    const __bf16* xrow = xb + ((size_t)(mt * 16 + j) * TT + t) * DD + q * 8;
    f32x4 acc[4];
#pragma unroll
    for (int g = 0; g < 4; ++g) acc[g] = (f32x4){bg[g], bg[g], bg[g], bg[g]};
#pragma unroll
    for (int kt = 0; kt < 8; ++kt) {
      bf16x8 a = *(const bf16x8*)(xrow + kt * 32);
#pragma unroll
      for (int g = 0; g < 4; ++g)
        acc[g] = __builtin_amdgcn_mfma_f32_16x16x32_bf16(a, wfrag[g][kt], acc[g], 0, 0, 0);
    }

    // wait until all blocks of this direction published h_tau (every wave spins)
    if (tau) {
      const unsigned int target = (unsigned int)tau;
      int iters = 0;
      for (;;) {
        unsigned int v = __hip_atomic_load(pollp, __ATOMIC_RELAXED, __HIP_MEMORY_SCOPE_AGENT);
        if (__all((int)(v >= target))) break;
        __builtin_amdgcn_s_sleep(1);
        if ((++iters & 63) == 63)  // progress insurance: occasional acquire (inv)
          (void)__hip_atomic_load(pollp, __ATOMIC_ACQUIRE, __HIP_MEMORY_SCOPE_AGENT);
      }
      __builtin_amdgcn_fence(__ATOMIC_ACQUIRE, "agent");
    }

    // h-part
    const __bf16* hrow = hb + (size_t)(tau & 1) * (BB * HH) + (size_t)(mt * 16 + j) * HH + q * 8;
#pragma unroll
    for (int kt = 0; kt < 16; ++kt) {
      bf16x8 a = *(const bf16x8*)(hrow + kt * 32);
#pragma unroll
      for (int g = 0; g < 4; ++g)
        acc[g] = __builtin_amdgcn_mfma_f32_16x16x32_bf16(a, wfrag[g][8 + kt], acc[g], 0, 0, 0);
    }

    // gates + state update + stores (all-sigmoid variant per reference)
    __bf16* hnext = hb + (size_t)((tau + 1) & 1) * (BB * HH);
#pragma unroll
    for (int r = 0; r < 4; ++r) {
      const float zi = acc[0][r], zf = acc[1][r], zg = acc[2][r], zo = acc[3][r];
      const float gi = sigf(zi), gf = sigf(zf), gg = sigf(zg), go = sigf(zo);
      const float cn = gf * cst[r] + gi * gg;
      cst[r] = cn;
      const float hn = go * sigf(cn);
      const int orow = mt * 16 + q * 4 + r;     // batch row
      __builtin_nontemporal_store((__bf16)hn, hnext + (size_t)orow * HH + colg);
      if (dir == 0) {
        __builtin_nontemporal_store(0.5f * hn,
            out + (size_t)orow * (TT * HH) + (size_t)t * HH + colg);
      } else {
        __builtin_nontemporal_store((__bf16)hn,
            hsb + (size_t)t * (BB * HH) + (size_t)orow * HH + colg);
      }
      if (tau == TT - 1) {
        float* base = out + outTail + (size_t)dir * (2 * BB * HH);
        __builtin_nontemporal_store(hn, base + (size_t)orow * HH + colg);            // hF/hB
        __builtin_nontemporal_store(cn, base + (size_t)BB * HH + (size_t)orow * HH + colg); // cF/cB
      }
    }

    __syncthreads();  // all waves done (stores vmcnt-drained at barrier)
    if (tid == 0) {
      __builtin_amdgcn_fence(__ATOMIC_RELEASE, "agent");
      __hip_atomic_store(myflag, (unsigned int)(tau + 1), __ATOMIC_RELAXED,
                         __HIP_MEMORY_SCOPE_AGENT);
    }
  }
}

// out[b,t,c] += 0.5 * hsb[t,b,c]
__global__ void combine_kernel(float* __restrict__ out, const __bf16* __restrict__ hsb) {
  const size_t i = ((size_t)blockIdx.x * 256 + threadIdx.x) * 4;
  const size_t b = i >> 18;
  const size_t t = (i >> 9) & 511;
  const size_t c = i & 511;
  bf16x4 hv = *(const bf16x4*)(hsb + t * (BB * HH) + b * HH + c);
  float4 v = *(float4*)(out + i);
  v.x += 0.5f * (float)hv[0];
  v.y += 0.5f * (float)hv[1];
  v.z += 0.5f * (float)hv[2];
  v.w += 0.5f * (float)hv[3];
  *(float4*)(out + i) = v;
}

extern "C" void kernel_launch(void* const* d_in, const int* in_sizes, int n_in,
                              void* d_out, int out_size, void* d_ws, size_t ws_size,
                              hipStream_t stream) {
  (void)in_sizes; (void)n_in; (void)out_size; (void)ws_size;
  const float* x   = (const float*)d_in[0];
  // d_in[1] = 'hidden' is unused by the reference (h0 = c0 = 0)
  const float* Wf  = (const float*)d_in[2];
  const float* Uf  = (const float*)d_in[3];
  const float* bf_ = (const float*)d_in[4];
  const float* Wb  = (const float*)d_in[5];
  const float* Ub  = (const float*)d_in[6];
  const float* bb_ = (const float*)d_in[7];
  float* out = (float*)d_out;
  char* ws = (char*)d_ws;

  // ws layout:
  //   [0, 8K)         : flags  2 dir x 32 blocks, 128B apart
  //   [8K, ~270K)     : hbuf   2 dir x 2 phase x 64 x 512 bf16
  //   [512K, 16.5M)   : x bf16 [B][T][D]
  //   [16.5M, 48.5M)  : hsb bf16 [T][B][H]
  unsigned int* flags = (unsigned int*)ws;
  __bf16* hbuf = (__bf16*)(ws + 8192);
  __bf16* xb   = (__bf16*)(ws + (1 << 19));
  __bf16* hsb  = (__bf16*)(ws + (1 << 19) + (size_t)BB * TT * DD * 2);

  hipMemsetAsync(ws, 0, 1 << 19, stream);  // zero flags + h ping-pong (h0 = 0)
  cvt_x_kernel<<<dim3((BB * TT * DD) / 1024), dim3(256), 0, stream>>>(x, xb);
  lstm_kernel<<<dim3(64), dim3(256), 0, stream>>>(xb, Wf, Uf, bf_, Wb, Ub, bb_,
                                                  hbuf, flags, out, hsb);
  combine_kernel<<<dim3((BB * TT * HH) / 1024), dim3(256), 0, stream>>>(out, hsb);
}

// Round 3
// 4392.283 us; speedup vs baseline: 1.0998x; 1.0998x over previous
//
#include <hip/hip_runtime.h>
#include <hip/hip_bf16.h>
#include <cstdint>
#include <cstddef>

#define BB 64
#define TT 512
#define DD 256
#define HH 512
#define G4 2048   // 4*H

typedef __bf16 bf16x8 __attribute__((ext_vector_type(8)));
typedef __bf16 bf16x4 __attribute__((ext_vector_type(4)));
typedef float  f32x4  __attribute__((ext_vector_type(4)));
typedef unsigned long long u64;

__device__ __forceinline__ float sigf(float x) {
  return 1.0f / (1.0f + __expf(-x));
}

__device__ __forceinline__ void drain_vmem() {
  asm volatile("s_waitcnt vmcnt(0)" ::: "memory");
}

// Convert x fp32 [B][T][D] -> bf16 (same layout) in ws.
__global__ void cvt_x_kernel(const float* __restrict__ x, __bf16* __restrict__ xb) {
  int i = (blockIdx.x * 256 + threadIdx.x) * 4;
  float4 v = *(const float4*)(x + i);
  bf16x4 o;
  o[0] = (__bf16)v.x; o[1] = (__bf16)v.y; o[2] = (__bf16)v.z; o[3] = (__bf16)v.w;
  *(bf16x4*)(xb + i) = o;
}

// Persistent bidirectional LSTM, fence-free cross-XCD sync.
// Grid: 64 blocks x 256 threads. dir = blockIdx>>5, s = blockIdx&31 owns hidden
// units [16s,16s+16). Wave = M-tile (16 batch rows). Weights pre-gathered as
// MFMA B-fragments in VGPR/AGPR.
// h exchange: write-through relaxed agent atomic stores (uint = 2 bf16 packed
// via shfl_xor), L2-bypass relaxed agent atomic uint64 loads. NO release/acquire
// fences -> no buffer_wbl2 / buffer_inv in the loop; L2 stays warm for xb.
// Per-wave s_waitcnt vmcnt(0) + __syncthreads orders h stores before the
// relaxed flag store.
__launch_bounds__(256, 1)
__global__ void lstm_kernel(const __bf16* __restrict__ xb,
                            const float* __restrict__ Wf, const float* __restrict__ Uf,
                            const float* __restrict__ bf_,
                            const float* __restrict__ Wb, const float* __restrict__ Ub,
                            const float* __restrict__ bb_,
                            __bf16* __restrict__ hbuf,           // [2 dir][2 phase][64][512]
                            unsigned int* __restrict__ flags,    // [2][32] stride 32 uints
                            float* __restrict__ out,             // d_out
                            __bf16* __restrict__ hsb) {          // [T][B][H] bwd halves
  const int bx  = blockIdx.x;
  const int dir = bx >> 5;
  const int s   = bx & 31;
  const float* Wd = dir ? Wb : Wf;
  const float* Ud = dir ? Ub : Uf;
  const float* bd = dir ? bb_ : bf_;
  unsigned int* flbase = flags + (size_t)dir * 32 * 32;   // 32 flags, 128B apart
  unsigned int* myflag = flbase + (size_t)s * 32;
  __bf16* hb = hbuf + (size_t)dir * 2 * BB * HH;

  const int tid  = threadIdx.x;
  const int mt   = tid >> 6;      // wave id = M-tile
  const int lane = tid & 63;
  const int j    = lane & 15;     // A row offset / B col / D col
  const int q    = lane >> 4;     // quad
  const int colg = s * 16 + j;    // hidden unit index this lane owns

  // ---- gather weight B-fragments (one-time) ----
  bf16x8 wfrag[4][24];
#pragma unroll
  for (int g = 0; g < 4; ++g) {
    const int col = g * HH + colg;
#pragma unroll
    for (int kt = 0; kt < 24; ++kt) {
      bf16x8 v;
#pragma unroll
      for (int e = 0; e < 8; ++e) {
        const int k = kt * 32 + q * 8 + e;
        const float w = (k < DD) ? Wd[(size_t)k * G4 + col]
                                 : Ud[(size_t)(k - DD) * G4 + col];
        v[e] = (__bf16)w;
      }
      wfrag[g][kt] = v;
    }
  }
  float bg[4];
#pragma unroll
  for (int g = 0; g < 4; ++g) bg[g] = bd[g * HH + colg];

  float cst[4] = {0.f, 0.f, 0.f, 0.f};   // cell state, rows mt*16+q*4+r
  const size_t outTail = (size_t)BB * TT * HH;
  unsigned int* pollp = flbase + (size_t)(lane & 31) * 32;

  for (int tau = 0; tau < TT; ++tau) {
    const int t = dir ? (TT - 1 - tau) : tau;

    // x-part (independent of h): issue before the spin
    const __bf16* xrow = xb + ((size_t)(mt * 16 + j) * TT + t) * DD + q * 8;
    f32x4 acc[4];
#pragma unroll
    for (int g = 0; g < 4; ++g) acc[g] = (f32x4){bg[g], bg[g], bg[g], bg[g]};
#pragma unroll
    for (int kt = 0; kt < 8; ++kt) {
      bf16x8 a = *(const bf16x8*)(xrow + kt * 32);
#pragma unroll
      for (int g = 0; g < 4; ++g)
        acc[g] = __builtin_amdgcn_mfma_f32_16x16x32_bf16(a, wfrag[g][kt], acc[g], 0, 0, 0);
    }

    // wait until all blocks of this direction published h_tau (every wave spins;
    // relaxed sc1 loads read the LLC directly -> always fresh, no inv needed)
    if (tau) {
      const unsigned int target = (unsigned int)tau;
      for (;;) {
        unsigned int v = __hip_atomic_load(pollp, __ATOMIC_RELAXED, __HIP_MEMORY_SCOPE_AGENT);
        if (__all((int)(v >= target))) break;
        __builtin_amdgcn_s_sleep(8);
      }
      asm volatile("" ::: "memory");   // compiler-only barrier; HW order via ctrl dep
    }

    // h-part: L2-bypassing 8B atomic loads straight from LLC
    const u64* hrow = (const u64*)(hb + (size_t)(tau & 1) * (BB * HH)
                                   + (size_t)(mt * 16 + j) * HH) + q * 2;
#pragma unroll
    for (int kt = 0; kt < 16; ++kt) {
      u64 lo = __hip_atomic_load(hrow + kt * 8,     __ATOMIC_RELAXED, __HIP_MEMORY_SCOPE_AGENT);
      u64 hi = __hip_atomic_load(hrow + kt * 8 + 1, __ATOMIC_RELAXED, __HIP_MEMORY_SCOPE_AGENT);
      union { u64 u[2]; bf16x8 v; } tmp;
      tmp.u[0] = lo; tmp.u[1] = hi;
#pragma unroll
      for (int g = 0; g < 4; ++g)
        acc[g] = __builtin_amdgcn_mfma_f32_16x16x32_bf16(tmp.v, wfrag[g][8 + kt], acc[g], 0, 0, 0);
    }

    // gates + state update + stores (all-sigmoid variant per reference)
    unsigned int* hnext = (unsigned int*)(hb + (size_t)((tau + 1) & 1) * (BB * HH));
#pragma unroll
    for (int r = 0; r < 4; ++r) {
      const float zi = acc[0][r], zf = acc[1][r], zg = acc[2][r], zo = acc[3][r];
      const float gi = sigf(zi), gf = sigf(zf), gg = sigf(zg), go = sigf(zo);
      const float cn = gf * cst[r] + gi * gg;
      cst[r] = cn;
      const float hn = go * sigf(cn);
      const int orow = mt * 16 + q * 4 + r;     // batch row

      // pack 2 adjacent units (lanes j, j^1 share q & rows) and write-through
      const unsigned int mine = (unsigned int)__builtin_bit_cast(unsigned short, (__bf16)hn);
      const unsigned int other = (unsigned int)__shfl_xor((int)mine, 1, 64);
      if (!(j & 1)) {
        const unsigned int packed = (other << 16) | mine;  // low addr = even unit
        __hip_atomic_store(hnext + ((size_t)orow * HH + colg) / 2, packed,
                           __ATOMIC_RELAXED, __HIP_MEMORY_SCOPE_AGENT);
      }

      if (dir == 0) {
        __builtin_nontemporal_store(0.5f * hn,
            out + (size_t)orow * (TT * HH) + (size_t)t * HH + colg);
      } else {
        __builtin_nontemporal_store((__bf16)hn,
            hsb + (size_t)t * (BB * HH) + (size_t)orow * HH + colg);
      }
      if (tau == TT - 1) {
        float* base = out + outTail + (size_t)dir * (2 * BB * HH);
        __builtin_nontemporal_store(hn, base + (size_t)orow * HH + colg);            // hF/hB
        __builtin_nontemporal_store(cn, base + (size_t)BB * HH + (size_t)orow * HH + colg); // cF/cB
      }
    }

    drain_vmem();      // this wave's h write-throughs acked by LLC
    __syncthreads();   // => whole block's h slice is globally visible
    if (tid == 0)
      __hip_atomic_store(myflag, (unsigned int)(tau + 1), __ATOMIC_RELAXED,
                         __HIP_MEMORY_SCOPE_AGENT);
  }
}

// out[b,t,c] += 0.5 * hsb[t,b,c]
__global__ void combine_kernel(float* __restrict__ out, const __bf16* __restrict__ hsb) {
  const size_t i = ((size_t)blockIdx.x * 256 + threadIdx.x) * 4;
  const size_t b = i >> 18;
  const size_t t = (i >> 9) & 511;
  const size_t c = i & 511;
  bf16x4 hv = *(const bf16x4*)(hsb + t * (BB * HH) + b * HH + c);
  float4 v = *(float4*)(out + i);
  v.x += 0.5f * (float)hv[0];
  v.y += 0.5f * (float)hv[1];
  v.z += 0.5f * (float)hv[2];
  v.w += 0.5f * (float)hv[3];
  *(float4*)(out + i) = v;
}

extern "C" void kernel_launch(void* const* d_in, const int* in_sizes, int n_in,
                              void* d_out, int out_size, void* d_ws, size_t ws_size,
                              hipStream_t stream) {
  (void)in_sizes; (void)n_in; (void)out_size; (void)ws_size;
  const float* x   = (const float*)d_in[0];
  // d_in[1] = 'hidden' is unused by the reference (h0 = c0 = 0)
  const float* Wf  = (const float*)d_in[2];
  const float* Uf  = (const float*)d_in[3];
  const float* bf_ = (const float*)d_in[4];
  const float* Wb  = (const float*)d_in[5];
  const float* Ub  = (const float*)d_in[6];
  const float* bb_ = (const float*)d_in[7];
  float* out = (float*)d_out;
  char* ws = (char*)d_ws;

  // ws layout:
  //   [0, 8K)         : flags  2 dir x 32 blocks, 128B apart
  //   [8K, ~270K)     : hbuf   2 dir x 2 phase x 64 x 512 bf16
  //   [512K, 16.5M)   : x bf16 [B][T][D]
  //   [16.5M, 48.5M)  : hsb bf16 [T][B][H]
  unsigned int* flags = (unsigned int*)ws;
  __bf16* hbuf = (__bf16*)(ws + 8192);
  __bf16* xb   = (__bf16*)(ws + (1 << 19));
  __bf16* hsb  = (__bf16*)(ws + (1 << 19) + (size_t)BB * TT * DD * 2);

  hipMemsetAsync(ws, 0, 1 << 19, stream);  // zero flags + h ping-pong (h0 = 0)
  cvt_x_kernel<<<dim3((BB * TT * DD) / 1024), dim3(256), 0, stream>>>(x, xb);
  lstm_kernel<<<dim3(64), dim3(256), 0, stream>>>(xb, Wf, Uf, bf_, Wb, Ub, bb_,
                                                  hbuf, flags, out, hsb);
  combine_kernel<<<dim3((BB * TT * HH) / 1024), dim3(256), 0, stream>>>(out, hsb);
}